// Round 5
// baseline (3427.226 us; speedup 1.0000x reference)
//
#include <hip/hip_runtime.h>
#include <math.h>

// MambaSlotAttention on MI355X — single persistent mega-kernel.
// logits = sn @ (SCALE*Wq@Wk^T) @ fn^T      (never materialize k)
// updates = ((attn^T @ fn) @ Wv) / mass     (never materialize v)
// All stages in ONE kernel with hand-rolled device-scope grid barriers;
// grid sized to co-residency via occupancy query (all blocks resident).

typedef __attribute__((ext_vector_type(8))) short bf16x8;
typedef __attribute__((ext_vector_type(4))) float f32x4;

#define SMEM_BYTES 51200
#define GELU_C 0.70710678118654752f

static __device__ __forceinline__ float bf2f(ushort u){
  union { unsigned int i; float f; } c; c.i = ((unsigned int)u) << 16; return c.f;
}
static __device__ __forceinline__ ushort f2bf(float x){
  union { float f; unsigned int i; } c; c.f = x;
  return (ushort)((c.i + 0x7fffu + ((c.i >> 16) & 1u)) >> 16);
}

struct MA {
  const float *features, *slots_init, *nf_g, *nf_b, *ns_g, *ns_b, *Wq, *Wk, *Wv;
  const float *mg, *mb, *mW1, *mb1, *mW2, *mb2;
  const float *b_ln1g, *b_ln1b, *b_Wqkv, *b_bqkv, *b_Wo, *b_bo;
  const float *b_ln2g, *b_ln2b, *b_W1, *b_b1, *b_W2, *b_b2;
  ushort *fnb, *Wq_bf, *WqkT, *WvT, *WqkvT, *WoT, *W1T, *W2T, *mW1T, *mW2T, *q2bf;
  float *slots, *sn, *h1, *qkvb, *ob, *x1, *h2, *m1, *s_in, *h3, *m2, *Ub, *Upart, *massb;
  float *out_slots, *out_masks;
  int *syncc, *syncg;
};

// ---------------- grid barrier (device-scope; all blocks co-resident) --------
static __device__ void gsync(int* cnt, int* gen, int nb){
  __syncthreads();
  if (threadIdx.x == 0){
    __threadfence();
    int g = __hip_atomic_load(gen, __ATOMIC_RELAXED, __HIP_MEMORY_SCOPE_AGENT);
    int v = __hip_atomic_fetch_add(cnt, 1, __ATOMIC_ACQ_REL, __HIP_MEMORY_SCOPE_AGENT);
    if (v == nb - 1){
      __hip_atomic_store(cnt, 0, __ATOMIC_RELAXED, __HIP_MEMORY_SCOPE_AGENT);
      __hip_atomic_fetch_add(gen, 1, __ATOMIC_ACQ_REL, __HIP_MEMORY_SCOPE_AGENT);
    } else {
      while (__hip_atomic_load(gen, __ATOMIC_ACQUIRE, __HIP_MEMORY_SCOPE_AGENT) == g)
        __builtin_amdgcn_s_sleep(8);
    }
    __threadfence();
  }
  __syncthreads();
}

// ---------------- LN stats over a 768-row held as 3 regs/thread --------------
static __device__ __forceinline__ void ln_stats3(float v0, float v1, float v2,
                                                 char* sm, float& mean, float& rstd){
  float s = v0+v1+v2, q = v0*v0+v1*v1+v2*v2;
  #pragma unroll
  for (int off=32; off>0; off>>=1){ s += __shfl_down(s,off); q += __shfl_down(q,off); }
  float* red = (float*)sm; float* mv = red + 8;
  const int tid = threadIdx.x, wave = tid>>6, lane = tid&63;
  if (lane==0){ red[wave]=s; red[4+wave]=q; }
  __syncthreads();
  if (tid==0){
    const float st = red[0]+red[1]+red[2]+red[3];
    const float qt = red[4]+red[5]+red[6]+red[7];
    const float m = st*(1.f/768.f);
    mv[0]=m; mv[1]=rsqrtf(qt*(1.f/768.f)-m*m + 1e-5f);
  }
  __syncthreads();
  mean = mv[0]; rstd = mv[1];
}

static __device__ __forceinline__ void dev_ln_f(const float* xr, const float* g,
                                                const float* b, float* yr, char* sm){
  const int tid = threadIdx.x;
  float v0=xr[tid], v1=xr[tid+256], v2=xr[tid+512];
  float m,r; ln_stats3(v0,v1,v2,sm,m,r);
  yr[tid]     = (v0-m)*r*g[tid]     + b[tid];
  yr[tid+256] = (v1-m)*r*g[tid+256] + b[tid+256];
  yr[tid+512] = (v2-m)*r*g[tid+512] + b[tid+512];
}

// ---------------- weight cvt job (hardcoded table) ---------------------------
static __device__ void dev_cvt(const MA& a, int j, char* sm){
  const int tid = threadIdx.x;
  if (j < 576){  // Wq straight copy
    const long base = (long)j*1024 + tid*4;
    const float4 v = *(const float4*)(a.Wq + base);
    ushort4 o; o.x=f2bf(v.x); o.y=f2bf(v.y); o.z=f2bf(v.z); o.w=f2bf(v.w);
    *(ushort4*)(a.Wq_bf + base) = o;
    return;
  }
  const float* src; ushort* dst; int R, C;
  if (j < 1152){ src=a.Wv; dst=a.WvT; R=768; C=768; j-=576; }
  else if (j < 6336){ int t=(j-1152)/1728; j=(j-1152)-t*1728;
    src=a.b_Wqkv+(size_t)t*768*2304; dst=a.WqkvT+(size_t)t*2304*768; R=768; C=2304; }
  else if (j < 8064){ int t=(j-6336)/576; j=(j-6336)-t*576;
    src=a.b_Wo+(size_t)t*589824; dst=a.WoT+(size_t)t*589824; R=768; C=768; }
  else if (j < 14976){ int t=(j-8064)/2304; j=(j-8064)-t*2304;
    src=a.b_W1+(size_t)t*768*3072; dst=a.W1T+(size_t)t*3072*768; R=768; C=3072; }
  else if (j < 21888){ int t=(j-14976)/2304; j=(j-14976)-t*2304;
    src=a.b_W2+(size_t)t*3072*768; dst=a.W2T+(size_t)t*768*3072; R=3072; C=768; }
  else if (j < 24192){ src=a.mW1; dst=a.mW1T; R=768; C=3072; j-=21888; }
  else { src=a.mW2; dst=a.mW2T; R=3072; C=768; j-=24192; }
  const int tpr = C>>5;
  const int tr = j/tpr, tc = j - tr*tpr;
  float* ts = (float*)sm;  // [32][33]
  const int r = tid>>3, c4 = (tid&7)<<2;
  const float4 v = *(const float4*)(src + (long)(tr*32 + r)*C + tc*32 + c4);
  ts[r*33+c4]=v.x; ts[r*33+c4+1]=v.y; ts[r*33+c4+2]=v.z; ts[r*33+c4+3]=v.w;
  __syncthreads();
  ushort4 o;
  o.x=f2bf(ts[(c4  )*33+r]); o.y=f2bf(ts[(c4+1)*33+r]);
  o.z=f2bf(ts[(c4+2)*33+r]); o.w=f2bf(ts[(c4+3)*33+r]);
  *(ushort4*)(dst + (long)(tc*32 + r)*R + tr*32 + c4) = o;
  __syncthreads();
}

// ---------------- MFMA 64x64 tile core: C += A(f32)@BT(bf16)^T ---------------
static __device__ void gemm_core(const float* __restrict__ A, const ushort* __restrict__ BT,
                                 int K, int m0, int n0, f32x4 acc[2][2], char* smch){
  ushort (*As)[72] = (ushort (*)[72])smch;
  ushort (*Bs)[72] = (ushort (*)[72])(smch + 9216);
  const int tid = threadIdx.x, lane = tid&63;
  const int wid = tid>>6, wr = wid>>1, wc = wid&1;
  const int sr = tid>>2, scol = (tid&3)<<4;
  const float*  Ap = A  + (long)(m0+sr)*K + scol;
  const ushort* Bp = BT + (long)(n0+sr)*K + scol;
  for (int k0=0; k0<K; k0+=64){
    const float4 a0 = *(const float4*)(Ap + k0);
    const float4 a1 = *(const float4*)(Ap + k0 + 4);
    const float4 a2 = *(const float4*)(Ap + k0 + 8);
    const float4 a3 = *(const float4*)(Ap + k0 + 12);
    const bf16x8 b0 = *(const bf16x8*)(Bp + k0);
    const bf16x8 b1 = *(const bf16x8*)(Bp + k0 + 8);
    bf16x8 w0, w1;
    w0[0]=(short)f2bf(a0.x); w0[1]=(short)f2bf(a0.y); w0[2]=(short)f2bf(a0.z); w0[3]=(short)f2bf(a0.w);
    w0[4]=(short)f2bf(a1.x); w0[5]=(short)f2bf(a1.y); w0[6]=(short)f2bf(a1.z); w0[7]=(short)f2bf(a1.w);
    w1[0]=(short)f2bf(a2.x); w1[1]=(short)f2bf(a2.y); w1[2]=(short)f2bf(a2.z); w1[3]=(short)f2bf(a2.w);
    w1[4]=(short)f2bf(a3.x); w1[5]=(short)f2bf(a3.y); w1[6]=(short)f2bf(a3.z); w1[7]=(short)f2bf(a3.w);
    *(bf16x8*)&As[sr][scol]   = w0;
    *(bf16x8*)&As[sr][scol+8] = w1;
    *(bf16x8*)&Bs[sr][scol]   = b0;
    *(bf16x8*)&Bs[sr][scol+8] = b1;
    __syncthreads();
    #pragma unroll
    for (int kk=0; kk<64; kk+=32){
      const int kr = kk + ((lane>>4)<<3);
      const bf16x8 aF0 = *(bf16x8*)&As[(wr<<5)      + (lane&15)][kr];
      const bf16x8 aF1 = *(bf16x8*)&As[(wr<<5) + 16 + (lane&15)][kr];
      const bf16x8 bF0 = *(bf16x8*)&Bs[(wc<<5)      + (lane&15)][kr];
      const bf16x8 bF1 = *(bf16x8*)&Bs[(wc<<5) + 16 + (lane&15)][kr];
      acc[0][0] = __builtin_amdgcn_mfma_f32_16x16x32_bf16(aF0, bF0, acc[0][0], 0,0,0);
      acc[0][1] = __builtin_amdgcn_mfma_f32_16x16x32_bf16(aF0, bF1, acc[0][1], 0,0,0);
      acc[1][0] = __builtin_amdgcn_mfma_f32_16x16x32_bf16(aF1, bF0, acc[1][0], 0,0,0);
      acc[1][1] = __builtin_amdgcn_mfma_f32_16x16x32_bf16(aF1, bF1, acc[1][1], 0,0,0);
    }
    __syncthreads();
  }
}

enum { F_BIAS=1, F_GELU=2, F_RESID=4, F_ROWSCALE=8, F_OUTBF16=16, F_PAD16=32 };

template<int FLAGS>
static __device__ void dev_gemm_tile(const float* A, const ushort* BT,
                                     float* C, ushort* Cbf, float* C2,
                                     int N, int K, int m0, int n0,
                                     const float* bias, const float* resid,
                                     const float* mass, float alpha, char* sm){
  f32x4 acc[2][2];
  #pragma unroll
  for (int i=0;i<2;i++){ acc[i][0]=(f32x4){0,0,0,0}; acc[i][1]=(f32x4){0,0,0,0}; }
  gemm_core(A, BT, K, m0, n0, acc, sm);
  const int tid=threadIdx.x, lane=tid&63, wid=tid>>6, wr=wid>>1, wc=wid&1;
  #pragma unroll
  for (int fm=0; fm<2; fm++)
    #pragma unroll
    for (int fn=0; fn<2; fn++){
      const int col = n0 + (wc<<5) + (fn<<4) + (lane&15);
      const float bia = (FLAGS & F_BIAS) ? bias[col] : 0.f;
      #pragma unroll
      for (int j=0;j<4;j++){
        const int row = m0 + (wr<<5) + (fm<<4) + ((lane>>4)<<2) + j;
        float cvl = acc[fm][fn][j]*alpha;
        if (FLAGS & F_ROWSCALE) cvl *= 1.f/fmaxf(mass[row], 1e-8f);
        cvl += bia;
        if (FLAGS & F_GELU) cvl = 0.5f*cvl*(1.f + erff(cvl*GELU_C));
        if (FLAGS & F_RESID) cvl += resid[(long)row*N + col];
        if (FLAGS & F_OUTBF16){
          const int orow = (FLAGS & F_PAD16) ? ((row/12)*16 + (row%12)) : row;
          Cbf[(long)orow*N + col] = f2bf(cvl);
        } else {
          C[(long)row*N + col] = cvl;
          if (C2) C2[(long)row*N + col] = cvl;
        }
      }
    }
}

// s_in = m1@W2T + b2 + x1 + (Ub@WvT)/mass
static __device__ void dev_dual_tile(const MA& a, int t, int m0, int n0, char* sm){
  f32x4 acc1[2][2], acc2[2][2];
  #pragma unroll
  for (int i=0;i<2;i++){ acc1[i][0]=(f32x4){0,0,0,0}; acc1[i][1]=(f32x4){0,0,0,0};
                         acc2[i][0]=(f32x4){0,0,0,0}; acc2[i][1]=(f32x4){0,0,0,0}; }
  gemm_core(a.m1, a.W2T + (long)t*768*3072, 3072, m0, n0, acc1, sm);
  gemm_core(a.Ub, a.WvT, 768, m0, n0, acc2, sm);
  const int tid=threadIdx.x, lane=tid&63, wid=tid>>6, wr=wid>>1, wc=wid&1;
  const float* b2 = a.b_b2 + t*768;
  #pragma unroll
  for (int fm=0; fm<2; fm++)
    #pragma unroll
    for (int fn=0; fn<2; fn++){
      const int col = n0 + (wc<<5) + (fn<<4) + (lane&15);
      const float bia = b2[col];
      #pragma unroll
      for (int j=0;j<4;j++){
        const int row = m0 + (wr<<5) + (fm<<4) + ((lane>>4)<<2) + j;
        const float inv = 1.f/fmaxf(a.massb[row], 1e-8f);
        a.s_in[(long)row*768 + col] =
            acc1[fm][fn][j] + bia + a.x1[(long)row*768 + col] + acc2[fm][fn][j]*inv;
      }
    }
}

// ---------------- fused attention sweep: logits+softmax(+mass,+U or masks) ---
// chunk = 32 n-rows; fn chunk staged in LDS with XOR swizzle (G4).
template<bool FINAL>
static __device__ void dev_sweep(const MA& a, int b, int ch, char* sm){
  __syncthreads();   // protect LDS reuse from previous job in this stage
  const int tid = threadIdx.x;
  const int n0 = ch*32;
  const int nn = min(32, 1369 - n0);
  float* lp = (float*)(sm + 49152);  // [32][16]
  for (int i = tid; i < 3072; i += 256){
    const int row = i/96;
    const int c8 = (i - row*96)*8;
    bf16x8 v = {0,0,0,0,0,0,0,0};
    if (row < nn)
      v = *(const bf16x8*)(a.fnb + ((long)(b*1369 + n0 + row))*768 + c8);
    const int off = (row*1536 + c8*2) ^ ((row&7)<<4);
    *(bf16x8*)(sm + off) = v;
  }
  __syncthreads();
  const int wave = tid>>6, lane = tid&63;
  if (wave < 2){
    f32x4 acc = {0,0,0,0};
    const ushort* qb = a.q2bf + (long)b*12288 + (long)(lane&15)*768 + ((lane>>4)<<3);
    const int rl = wave*16 + (lane&15);
    const int kof = (lane>>4)<<3;
    #pragma unroll 4
    for (int dk=0; dk<768; dk+=32){
      const bf16x8 av = *(const bf16x8*)(qb + dk);
      const int off = (rl*1536 + (dk + kof)*2) ^ ((rl&7)<<4);
      const bf16x8 bv = *(bf16x8*)(sm + off);
      acc = __builtin_amdgcn_mfma_f32_16x16x32_bf16(av, bv, acc, 0,0,0);
    }
    #pragma unroll
    for (int j=0;j<4;j++)
      lp[rl*16 + ((lane>>4)<<2) + j] = acc[j];
  }
  __syncthreads();
  if (tid < nn){
    float lg[12]; float mx = -1e30f;
    #pragma unroll
    for (int k=0;k<12;k++){ lg[k] = lp[tid*16+k]; mx = fmaxf(mx, lg[k]); }
    float ss = 0.f;
    #pragma unroll
    for (int k=0;k<12;k++){ lg[k] = expf(lg[k]-mx); ss += lg[k]; }
    const float inv = 1.f/ss;
    #pragma unroll
    for (int k=0;k<12;k++) lp[tid*16+k] = lg[k]*inv;
  }
  __syncthreads();
  if (FINAL){
    for (int i = tid; i < nn*12; i += 256){
      const int n = i/12, k = i - n*12;
      a.out_masks[((long)(b*1369 + n0 + n))*12 + k] = lp[n*16+k];
    }
    return;
  }
  if (tid < 12){
    float s = 0.f;
    for (int n=0; n<nn; n++) s += lp[n*16+tid];
    atomicAdd(a.massb + b*12 + tid, s);
  }
  float u[36];
  #pragma unroll
  for (int i=0;i<36;i++) u[i] = 0.f;
  for (int n=0; n<nn; n++){
    float p[12];
    #pragma unroll
    for (int k=0;k<12;k++) p[k] = lp[n*16+k];
    #pragma unroll
    for (int c=0;c<3;c++){
      const int d = tid + (c<<8);
      const ushort fv = *(const ushort*)(sm + ((n*1536 + d*2) ^ ((n&7)<<4)));
      const float f = bf2f(fv);
      #pragma unroll
      for (int k=0;k<12;k++) u[k*3+c] += p[k]*f;
    }
  }
  float* up = a.Upart + (long)(b*43 + ch)*9216;
  #pragma unroll
  for (int k=0;k<12;k++)
    #pragma unroll
    for (int c=0;c<3;c++)
      up[k*768 + tid + (c<<8)] = u[k*3+c];
}

// ---------------- slot self-attention (one (b,h) pair) -----------------------
static __device__ void dev_slotattn(const MA& a, int b, int h, char* sm){
  __syncthreads();
  float* qs = (float*)sm;      // [12][100]
  float* ks = qs + 1200;
  float* vs = ks + 1200;
  float* sc = vs + 1200;       // [12][16]
  const int tid = threadIdx.x;
  for (int idx = tid; idx < 1152; idx += 256){
    const int i = idx/96, d = idx - i*96;
    const float* base = a.qkvb + (long)(b*12+i)*2304 + h*96 + d;
    qs[i*100+d] = base[0];
    ks[i*100+d] = base[768];
    vs[i*100+d] = base[1536];
  }
  __syncthreads();
  if (tid < 144){
    const int i = tid/12, j = tid - i*12;
    float s = 0.f;
    #pragma unroll 8
    for (int d=0; d<96; d++) s += qs[i*100+d]*ks[j*100+d];
    sc[i*16+j] = s * 0.10206207261596575f;
  }
  __syncthreads();
  if (tid < 12){
    float mx = -1e30f;
    #pragma unroll
    for (int j=0;j<12;j++) mx = fmaxf(mx, sc[tid*16+j]);
    float e[12], ss = 0.f;
    #pragma unroll
    for (int j=0;j<12;j++){ e[j] = expf(sc[tid*16+j]-mx); ss += e[j]; }
    const float inv = 1.f/ss;
    #pragma unroll
    for (int j=0;j<12;j++) sc[tid*16+j] = e[j]*inv;
  }
  __syncthreads();
  for (int idx = tid; idx < 1152; idx += 256){
    const int i = idx/96, d = idx - i*96;
    float s = 0.f;
    #pragma unroll
    for (int j=0;j<12;j++) s += sc[i*16+j]*vs[j*100+d];
    a.ob[(long)(b*12+i)*768 + h*96 + d] = s;
  }
  __syncthreads();
}

// ---------------- the mega kernel --------------------------------------------
__global__ __launch_bounds__(256, 2) void mega_kernel(MA a){
  extern __shared__ char sm[];
  const int bid = blockIdx.x, nb = gridDim.x, tid = threadIdx.x;
  int* cnt = a.syncc; int* gen = a.syncg;
  const float SCALEF = 0.03608439182435161f;  // 768^-0.5

  // ---- S0: weight cvt + fn LN + slots copy + q2 pad zero
  for (int j = bid; j < 26496; j += nb) dev_cvt(a, j, sm);
  for (int r = bid; r < 43808; r += nb){
    const float* xr = a.features + (long)r*768;
    float v0=xr[tid], v1=xr[tid+256], v2=xr[tid+512];
    float m, rs; ln_stats3(v0,v1,v2,sm,m,rs);
    a.fnb[(long)r*768 + tid]     = f2bf((v0-m)*rs*a.nf_g[tid]     + a.nf_b[tid]);
    a.fnb[(long)r*768 + tid+256] = f2bf((v1-m)*rs*a.nf_g[tid+256] + a.nf_b[tid+256]);
    a.fnb[(long)r*768 + tid+512] = f2bf((v2-m)*rs*a.nf_g[tid+512] + a.nf_b[tid+512]);
  }
  for (int o = bid*256 + tid; o < 294912; o += nb*256) a.slots[o] = a.slots_init[o];
  for (int o = bid*256 + tid; o < 98304; o += nb*256){
    const int b = o/3072, rem = o - b*3072;
    a.q2bf[(long)(b*16 + 12 + rem/768)*768 + (rem%768)] = 0;
  }
  gsync(cnt, gen, nb);

  // ---- S0b: WqkT = SCALE * Wk @ Wq^T (bf16 out)
  for (int j = bid; j < 144; j += nb)
    dev_gemm_tile<F_OUTBF16>(a.Wk, a.Wq_bf, nullptr, a.WqkT, nullptr,
                             768, 768, (j/12)<<6, (j%12)<<6,
                             nullptr, nullptr, nullptr, SCALEF, sm);
  gsync(cnt, gen, nb);

  for (int t = 0; t < 3; t++){
    // ---- S1: sn = ln(slots); h1 = ln(sn, ln1); massb = 0
    for (int j = bid; j <= 384; j += nb){
      if (j < 384){
        const float* xr = a.slots + (long)j*768;
        float v0=xr[tid], v1=xr[tid+256], v2=xr[tid+512];
        float m, r; ln_stats3(v0,v1,v2,sm,m,r);
        const float s0 = (v0-m)*r*a.ns_g[tid]     + a.ns_b[tid];
        const float s1 = (v1-m)*r*a.ns_g[tid+256] + a.ns_b[tid+256];
        const float s2 = (v2-m)*r*a.ns_g[tid+512] + a.ns_b[tid+512];
        a.sn[(long)j*768+tid]=s0; a.sn[(long)j*768+tid+256]=s1; a.sn[(long)j*768+tid+512]=s2;
        float m2, r2; ln_stats3(s0,s1,s2,sm,m2,r2);
        const float* g1 = a.b_ln1g + t*768; const float* bb1 = a.b_ln1b + t*768;
        a.h1[(long)j*768+tid]     = (s0-m2)*r2*g1[tid]     + bb1[tid];
        a.h1[(long)j*768+tid+256] = (s1-m2)*r2*g1[tid+256] + bb1[tid+256];
        a.h1[(long)j*768+tid+512] = (s2-m2)*r2*g1[tid+512] + bb1[tid+512];
      } else {
        if (tid < 384) a.massb[tid] = 0.f;
      }
    }
    gsync(cnt, gen, nb);
    // ---- S2: q2 = sn@WqkT (bf16, PAD16) || qkv = h1@WqkvT + bqkv
    for (int j = bid; j < 288; j += nb){
      if (j < 72)
        dev_gemm_tile<F_OUTBF16|F_PAD16>(a.sn, a.WqkT, nullptr, a.q2bf, nullptr,
                                         768, 768, (j/12)<<6, (j%12)<<6,
                                         nullptr, nullptr, nullptr, 1.f, sm);
      else {
        const int jj = j - 72;
        dev_gemm_tile<F_BIAS>(a.h1, a.WqkvT + (long)t*2304*768, a.qkvb, nullptr, nullptr,
                              2304, 768, (jj/36)<<6, (jj%36)<<6,
                              a.b_bqkv + t*2304, nullptr, nullptr, 1.f, sm);
      }
    }
    gsync(cnt, gen, nb);
    // ---- S3: attention sweep (1376 jobs) || slot self-attn (256 jobs)
    for (int j = bid; j < 1632; j += nb){
      if (j < 1376) dev_sweep<false>(a, j/43, j%43, sm);
      else { const int jj = j - 1376; dev_slotattn(a, jj>>3, jj&7, sm); }
    }
    gsync(cnt, gen, nb);
    // ---- S4: x1 = ob@WoT + bo + sn  ||  Ub = sum_ch Upart
    for (int j = bid; j < 72; j += nb)
      dev_gemm_tile<F_BIAS|F_RESID>(a.ob, a.WoT + (long)t*589824, a.x1, nullptr, nullptr,
                                    768, 768, (j/12)<<6, (j%12)<<6,
                                    a.b_bo + t*768, a.sn, nullptr, 1.f, sm);
    for (int o = bid*256 + tid; o < 294912; o += nb*256){
      const int b = o/9216, r = o - b*9216;
      const float* up = a.Upart + (long)b*43*9216 + r;
      float s = 0.f;
      for (int c=0; c<43; c++) s += up[(long)c*9216];
      a.Ub[o] = s;
    }
    gsync(cnt, gen, nb);
    // ---- S5: h2 = ln(x1, ln2)
    for (int j = bid; j < 384; j += nb)
      dev_ln_f(a.x1 + (long)j*768, a.b_ln2g + t*768, a.b_ln2b + t*768, a.h2 + (long)j*768, sm);
    gsync(cnt, gen, nb);
    // ---- S6: m1 = gelu(h2@W1T + b1)
    for (int j = bid; j < 288; j += nb)
      dev_gemm_tile<F_BIAS|F_GELU>(a.h2, a.W1T + (long)t*3072*768, a.m1, nullptr, nullptr,
                                   3072, 768, (j/48)<<6, (j%48)<<6,
                                   a.b_b1 + t*3072, nullptr, nullptr, 1.f, sm);
    gsync(cnt, gen, nb);
    // ---- S7: s_in = m1@W2T + b2 + x1 + (Ub@WvT)/mass
    for (int j = bid; j < 72; j += nb)
      dev_dual_tile(a, t, (j/12)<<6, (j%12)<<6, sm);
    gsync(cnt, gen, nb);
    // ---- S8: h3 = ln(s_in, mg, mb)
    for (int j = bid; j < 384; j += nb)
      dev_ln_f(a.s_in + (long)j*768, a.mg, a.mb, a.h3 + (long)j*768, sm);
    gsync(cnt, gen, nb);
    // ---- S9: m2 = gelu(h3@mW1T + mb1)
    for (int j = bid; j < 288; j += nb)
      dev_gemm_tile<F_BIAS|F_GELU>(a.h3, a.mW1T, a.m2, nullptr, nullptr,
                                   3072, 768, (j/48)<<6, (j%48)<<6,
                                   a.mb1, nullptr, nullptr, 1.f, sm);
    gsync(cnt, gen, nb);
    // ---- S10: slots += m2@mW2T + mb2 (t==2: also write d_out)
    for (int j = bid; j < 72; j += nb)
      dev_gemm_tile<F_BIAS|F_RESID>(a.m2, a.mW2T, a.slots, nullptr,
                                    (t==2) ? a.out_slots : nullptr,
                                    768, 3072, (j/12)<<6, (j%12)<<6,
                                    a.mb2, a.slots, nullptr, 1.f, sm);
    gsync(cnt, gen, nb);
  }

  // ---- F1: sn = ln(slots)
  for (int j = bid; j < 384; j += nb)
    dev_ln_f(a.slots + (long)j*768, a.ns_g, a.ns_b, a.sn + (long)j*768, sm);
  gsync(cnt, gen, nb);
  // ---- F2: q2 = sn@WqkT
  for (int j = bid; j < 72; j += nb)
    dev_gemm_tile<F_OUTBF16|F_PAD16>(a.sn, a.WqkT, nullptr, a.q2bf, nullptr,
                                     768, 768, (j/12)<<6, (j%12)<<6,
                                     nullptr, nullptr, nullptr, 1.f, sm);
  gsync(cnt, gen, nb);
  // ---- F3: final masks
  for (int j = bid; j < 1376; j += nb)
    dev_sweep<true>(a, j/43, j%43, sm);
}

// ---------------- host -------------------------------------------------------
extern "C" void kernel_launch(void* const* d_in, const int* in_sizes, int n_in,
                              void* d_out, int out_size, void* d_ws, size_t ws_size,
                              hipStream_t stream){
  (void)in_sizes; (void)n_in; (void)out_size; (void)ws_size;
  MA a;
  a.features  = (const float*)d_in[0];
  a.slots_init= (const float*)d_in[1];
  a.nf_g = (const float*)d_in[2];  a.nf_b = (const float*)d_in[3];
  a.ns_g = (const float*)d_in[4];  a.ns_b = (const float*)d_in[5];
  a.Wq   = (const float*)d_in[6];  a.Wk   = (const float*)d_in[7];
  a.Wv   = (const float*)d_in[8];
  a.mg   = (const float*)d_in[9];  a.mb   = (const float*)d_in[10];
  a.mW1  = (const float*)d_in[11]; a.mb1  = (const float*)d_in[12];
  a.mW2  = (const float*)d_in[13]; a.mb2  = (const float*)d_in[14];
  a.b_ln1g = (const float*)d_in[15]; a.b_ln1b = (const float*)d_in[16];
  a.b_Wqkv = (const float*)d_in[17]; a.b_bqkv = (const float*)d_in[18];
  a.b_Wo   = (const float*)d_in[19]; a.b_bo   = (const float*)d_in[20];
  a.b_ln2g = (const float*)d_in[21]; a.b_ln2b = (const float*)d_in[22];
  a.b_W1   = (const float*)d_in[23]; a.b_b1   = (const float*)d_in[24];
  a.b_W2   = (const float*)d_in[25]; a.b_b2   = (const float*)d_in[26];

  char* ws = (char*)d_ws;
  size_t off = 0;
  auto alloc = [&](size_t bytes)->char*{
    char* p = ws + off; off += (bytes + 255) & ~(size_t)255; return p;
  };
  char* sbuf = alloc(256);
  a.syncc = (int*)sbuf;
  a.syncg = (int*)(sbuf + 128);
  a.fnb   = (ushort*)alloc(43808ull*768*2);
  a.Wq_bf = (ushort*)alloc(589824ull*2);
  a.WqkT  = (ushort*)alloc(589824ull*2);
  a.WvT   = (ushort*)alloc(589824ull*2);
  a.WqkvT = (ushort*)alloc(3ull*2304*768*2);
  a.WoT   = (ushort*)alloc(3ull*589824*2);
  a.W1T   = (ushort*)alloc(3ull*3072*768*2);
  a.W2T   = (ushort*)alloc(3ull*3072*768*2);
  a.mW1T  = (ushort*)alloc(3072ull*768*2);
  a.mW2T  = (ushort*)alloc(3072ull*768*2);
  a.q2bf  = (ushort*)alloc(32ull*16*768*2);
  a.slots = (float*)alloc(294912ull*4);
  a.sn    = (float*)alloc(294912ull*4);
  a.h1    = (float*)alloc(294912ull*4);
  a.qkvb  = (float*)alloc(384ull*2304*4);
  a.ob    = (float*)alloc(294912ull*4);
  a.x1    = (float*)alloc(294912ull*4);
  a.h2    = (float*)alloc(294912ull*4);
  a.m1    = (float*)alloc(384ull*3072*4);
  a.s_in  = (float*)alloc(294912ull*4);
  a.h3    = (float*)alloc(294912ull*4);
  a.m2    = (float*)alloc(384ull*3072*4);
  a.Ub    = (float*)alloc(294912ull*4);
  a.Upart = (float*)alloc(32ull*43*9216*4);
  a.massb = (float*)alloc(384ull*4);
  a.out_slots = (float*)d_out;
  a.out_masks = (float*)d_out + 294912;

  hipMemsetAsync(sbuf, 0, 256, stream);

  int nbpc = 0;
  hipError_t e = hipOccupancyMaxActiveBlocksPerMultiprocessor(&nbpc, mega_kernel, 256,
                                                              (size_t)SMEM_BYTES);
  if (e != hipSuccess || nbpc < 1) nbpc = 1;
  int grid = nbpc * 256;
  if (grid > 512) grid = 512;
  mega_kernel<<<dim3(grid), dim3(256), SMEM_BYTES, stream>>>(a);
}

// Round 6
// 1048.238 us; speedup vs baseline: 3.2695x; 3.2695x over previous
//
#include <hip/hip_runtime.h>
#include <math.h>

// MambaSlotAttention on MI355X — multi-kernel (proven skeleton) + fusions.
// logits = sn @ (SCALE*Wq@Wk^T) @ fn^T      (never materialize k)
// updates = ((attn^T @ fn) @ Wv) / mass     (never materialize v)

typedef __attribute__((ext_vector_type(8))) short bf16x8;
typedef __attribute__((ext_vector_type(4))) float f32x4;
#define GELU_C 0.70710678118654752f

static __device__ __forceinline__ float bf2f(ushort u){
  union { unsigned int i; float f; } c; c.i = ((unsigned int)u) << 16; return c.f;
}
static __device__ __forceinline__ ushort f2bf(float x){
  union { float f; unsigned int i; } c; c.f = x;
  return (ushort)((c.i + 0x7fffu + ((c.i >> 16) & 1u)) >> 16);
}

struct MA {
  const float *features, *slots_init, *nf_g, *nf_b, *ns_g, *ns_b, *Wq, *Wk, *Wv;
  const float *mg, *mb, *mW1, *mb1, *mW2, *mb2;
  const float *b_ln1g, *b_ln1b, *b_Wqkv, *b_bqkv, *b_Wo, *b_bo;
  const float *b_ln2g, *b_ln2b, *b_W1, *b_b1, *b_W2, *b_b2;
  ushort *fnb, *Wq_bf, *WqkT, *WvT, *WqkvT, *WoT, *W1T, *W2T, *mW1T, *mW2T, *q2bf;
  float *slots, *sn, *h1, *qkvb, *ob, *x1, *h2, *m1, *s_in, *h3, *m2;
  float *Ub, *Upart, *massp, *invmass;
  float *out_slots, *out_masks;
};

// ---------------- LN stats (768-row in 3 regs/thread, 256-thr block) ---------
static __device__ __forceinline__ void ln_stats3(float v0, float v1, float v2,
                                                 float* red, float& mean, float& rstd){
  float s = v0+v1+v2, q = v0*v0+v1*v1+v2*v2;
  #pragma unroll
  for (int off=32; off>0; off>>=1){ s += __shfl_down(s,off); q += __shfl_down(q,off); }
  const int tid = threadIdx.x, wave = tid>>6, lane = tid&63;
  if (lane==0){ red[wave]=s; red[4+wave]=q; }
  __syncthreads();
  if (tid==0){
    const float st = red[0]+red[1]+red[2]+red[3];
    const float qt = red[4]+red[5]+red[6]+red[7];
    const float m = st*(1.f/768.f);
    red[8]=m; red[9]=rsqrtf(qt*(1.f/768.f)-m*m + 1e-5f);
  }
  __syncthreads();
  mean = red[8]; rstd = red[9];
}

// ---------------- weight cvt job (hardcoded table) ---------------------------
static __device__ void dev_cvt(const MA& a, int j, float* ts){
  const int tid = threadIdx.x;
  if (j < 576){  // Wq straight copy
    const long base = (long)j*1024 + tid*4;
    const float4 v = *(const float4*)(a.Wq + base);
    ushort4 o; o.x=f2bf(v.x); o.y=f2bf(v.y); o.z=f2bf(v.z); o.w=f2bf(v.w);
    *(ushort4*)(a.Wq_bf + base) = o;
    return;
  }
  const float* src; ushort* dst; int R, C;
  if (j < 1152){ src=a.Wv; dst=a.WvT; R=768; C=768; j-=576; }
  else if (j < 6336){ int t=(j-1152)/1728; j=(j-1152)-t*1728;
    src=a.b_Wqkv+(size_t)t*768*2304; dst=a.WqkvT+(size_t)t*2304*768; R=768; C=2304; }
  else if (j < 8064){ int t=(j-6336)/576; j=(j-6336)-t*576;
    src=a.b_Wo+(size_t)t*589824; dst=a.WoT+(size_t)t*589824; R=768; C=768; }
  else if (j < 14976){ int t=(j-8064)/2304; j=(j-8064)-t*2304;
    src=a.b_W1+(size_t)t*768*3072; dst=a.W1T+(size_t)t*3072*768; R=768; C=3072; }
  else if (j < 21888){ int t=(j-14976)/2304; j=(j-14976)-t*2304;
    src=a.b_W2+(size_t)t*3072*768; dst=a.W2T+(size_t)t*768*3072; R=3072; C=768; }
  else if (j < 24192){ src=a.mW1; dst=a.mW1T; R=768; C=3072; j-=21888; }
  else { src=a.mW2; dst=a.mW2T; R=3072; C=768; j-=24192; }
  const int tpr = C>>5;
  const int tr = j/tpr, tc = j - tr*tpr;
  const int r = tid>>3, c4 = (tid&7)<<2;
  const float4 v = *(const float4*)(src + (long)(tr*32 + r)*C + tc*32 + c4);
  ts[r*33+c4]=v.x; ts[r*33+c4+1]=v.y; ts[r*33+c4+2]=v.z; ts[r*33+c4+3]=v.w;
  __syncthreads();
  ushort4 o;
  o.x=f2bf(ts[(c4  )*33+r]); o.y=f2bf(ts[(c4+1)*33+r]);
  o.z=f2bf(ts[(c4+2)*33+r]); o.w=f2bf(ts[(c4+3)*33+r]);
  *(ushort4*)(dst + (long)(tc*32 + r)*R + tr*32 + c4) = o;
}

// ---------------- MFMA 64x64 tile core with k-prefetch -----------------------
// C += A(f32)@BT(bf16)^T. Loads for step k+1 are issued before step k's MFMA.
static __device__ void gemm_core(const float* __restrict__ A, const ushort* __restrict__ BT,
                                 int K, int m0, int n0, f32x4 acc[2][2], char* smch){
  ushort (*As)[72] = (ushort (*)[72])smch;
  ushort (*Bs)[72] = (ushort (*)[72])(smch + 9216);
  const int tid = threadIdx.x, lane = tid&63;
  const int wid = tid>>6, wr = wid>>1, wc = wid&1;
  const int sr = tid>>2, scol = (tid&3)<<4;
  const float*  Ap = A  + (long)(m0+sr)*K + scol;
  const ushort* Bp = BT + (long)(n0+sr)*K + scol;
  float4 a0 = *(const float4*)(Ap);
  float4 a1 = *(const float4*)(Ap + 4);
  float4 a2 = *(const float4*)(Ap + 8);
  float4 a3 = *(const float4*)(Ap + 12);
  bf16x8 b0 = *(const bf16x8*)(Bp);
  bf16x8 b1 = *(const bf16x8*)(Bp + 8);
  for (int k0=0; k0<K; k0+=64){
    bf16x8 w0, w1;
    w0[0]=(short)f2bf(a0.x); w0[1]=(short)f2bf(a0.y); w0[2]=(short)f2bf(a0.z); w0[3]=(short)f2bf(a0.w);
    w0[4]=(short)f2bf(a1.x); w0[5]=(short)f2bf(a1.y); w0[6]=(short)f2bf(a1.z); w0[7]=(short)f2bf(a1.w);
    w1[0]=(short)f2bf(a2.x); w1[1]=(short)f2bf(a2.y); w1[2]=(short)f2bf(a2.z); w1[3]=(short)f2bf(a2.w);
    w1[4]=(short)f2bf(a3.x); w1[5]=(short)f2bf(a3.y); w1[6]=(short)f2bf(a3.z); w1[7]=(short)f2bf(a3.w);
    __syncthreads();           // previous MFMA phase done reading LDS
    *(bf16x8*)&As[sr][scol]   = w0;
    *(bf16x8*)&As[sr][scol+8] = w1;
    *(bf16x8*)&Bs[sr][scol]   = b0;
    *(bf16x8*)&Bs[sr][scol+8] = b1;
    __syncthreads();
    if (k0 + 64 < K){          // prefetch next step (in flight during MFMA)
      a0 = *(const float4*)(Ap + k0 + 64);
      a1 = *(const float4*)(Ap + k0 + 68);
      a2 = *(const float4*)(Ap + k0 + 72);
      a3 = *(const float4*)(Ap + k0 + 76);
      b0 = *(const bf16x8*)(Bp + k0 + 64);
      b1 = *(const bf16x8*)(Bp + k0 + 72);
    }
    #pragma unroll
    for (int kk=0; kk<64; kk+=32){
      const int kr = kk + ((lane>>4)<<3);
      const bf16x8 aF0 = *(bf16x8*)&As[(wr<<5)      + (lane&15)][kr];
      const bf16x8 aF1 = *(bf16x8*)&As[(wr<<5) + 16 + (lane&15)][kr];
      const bf16x8 bF0 = *(bf16x8*)&Bs[(wc<<5)      + (lane&15)][kr];
      const bf16x8 bF1 = *(bf16x8*)&Bs[(wc<<5) + 16 + (lane&15)][kr];
      acc[0][0] = __builtin_amdgcn_mfma_f32_16x16x32_bf16(aF0, bF0, acc[0][0], 0,0,0);
      acc[0][1] = __builtin_amdgcn_mfma_f32_16x16x32_bf16(aF0, bF1, acc[0][1], 0,0,0);
      acc[1][0] = __builtin_amdgcn_mfma_f32_16x16x32_bf16(aF1, bF0, acc[1][0], 0,0,0);
      acc[1][1] = __builtin_amdgcn_mfma_f32_16x16x32_bf16(aF1, bF1, acc[1][1], 0,0,0);
    }
  }
}

enum { F_BIAS=1, F_GELU=2, F_RESID=4, F_OUTBF16=16, F_PAD16=32 };

template<int FLAGS>
static __device__ void dev_gemm_tile(const float* A, const ushort* BT,
                                     float* C, ushort* Cbf, float* C2,
                                     int N, int K, int m0, int n0,
                                     const float* bias, const float* resid,
                                     float alpha, char* sm){
  f32x4 acc[2][2];
  #pragma unroll
  for (int i=0;i<2;i++){ acc[i][0]=(f32x4){0,0,0,0}; acc[i][1]=(f32x4){0,0,0,0}; }
  gemm_core(A, BT, K, m0, n0, acc, sm);
  const int tid=threadIdx.x, lane=tid&63, wid=tid>>6, wr=wid>>1, wc=wid&1;
  #pragma unroll
  for (int fm=0; fm<2; fm++)
    #pragma unroll
    for (int fn=0; fn<2; fn++){
      const int col = n0 + (wc<<5) + (fn<<4) + (lane&15);
      const float bia = (FLAGS & F_BIAS) ? bias[col] : 0.f;
      #pragma unroll
      for (int j=0;j<4;j++){
        const int row = m0 + (wr<<5) + (fm<<4) + ((lane>>4)<<2) + j;
        float cvl = acc[fm][fn][j]*alpha + bia;
        if (FLAGS & F_GELU) cvl = 0.5f*cvl*(1.f + erff(cvl*GELU_C));
        if (FLAGS & F_RESID) cvl += resid[(long)row*N + col];
        if (FLAGS & F_OUTBF16){
          const int orow = (FLAGS & F_PAD16) ? ((row/12)*16 + (row%12)) : row;
          Cbf[(long)orow*N + col] = f2bf(cvl);
        } else {
          C[(long)row*N + col] = cvl;
          if (C2) C2[(long)row*N + col] = cvl;
        }
      }
    }
}

// ---------------- fused attention sweep ---------------------------------------
// chunk = 32 n-rows; fn staged in LDS (XOR swizzle); logits+softmax+(mass,U) or masks.
template<bool FINAL>
static __device__ void dev_sweep(const MA& a, int b, int ch, char* sm){
  const int tid = threadIdx.x;
  const int n0 = ch*32;
  const int nn = min(32, 1369 - n0);
  float* lp = (float*)(sm + 49152);  // [32][16]
  #pragma unroll
  for (int i = tid; i < 3072; i += 256){
    const int row = i/96;
    const int c8 = (i - row*96)*8;
    bf16x8 v = {0,0,0,0,0,0,0,0};
    if (row < nn)
      v = *(const bf16x8*)(a.fnb + ((long)(b*1369 + n0 + row))*768 + c8);
    const int off = (row*1536 + c8*2) ^ ((row&7)<<4);
    *(bf16x8*)(sm + off) = v;
  }
  __syncthreads();
  const int wave = tid>>6, lane = tid&63;
  if (wave < 2){
    f32x4 acc = {0,0,0,0};
    const ushort* qb = a.q2bf + (long)b*12288 + (long)(lane&15)*768 + ((lane>>4)<<3);
    const int rl = wave*16 + (lane&15);
    const int kof = (lane>>4)<<3;
    #pragma unroll 4
    for (int dk=0; dk<768; dk+=32){
      const bf16x8 av = *(const bf16x8*)(qb + dk);
      const int off = (rl*1536 + (dk + kof)*2) ^ ((rl&7)<<4);
      const bf16x8 bv = *(bf16x8*)(sm + off);
      acc = __builtin_amdgcn_mfma_f32_16x16x32_bf16(av, bv, acc, 0,0,0);
    }
    #pragma unroll
    for (int j=0;j<4;j++)
      lp[rl*16 + ((lane>>4)<<2) + j] = acc[j];
  }
  __syncthreads();
  if (tid < nn){
    float lg[12]; float mx = -1e30f;
    #pragma unroll
    for (int k=0;k<12;k++){ lg[k] = lp[tid*16+k]; mx = fmaxf(mx, lg[k]); }
    float ss = 0.f;
    #pragma unroll
    for (int k=0;k<12;k++){ lg[k] = expf(lg[k]-mx); ss += lg[k]; }
    const float inv = 1.f/ss;
    #pragma unroll
    for (int k=0;k<12;k++) lp[tid*16+k] = lg[k]*inv;
  }
  __syncthreads();
  if (FINAL){
    for (int i = tid; i < nn*12; i += 256){
      const int n = i/12, k = i - n*12;
      a.out_masks[((long)(b*1369 + n0 + n))*12 + k] = lp[n*16+k];
    }
    return;
  }
  if (tid < 12){
    float s = 0.f;
    for (int n=0; n<nn; n++) s += lp[n*16+tid];
    a.massp[(long)(b*43 + ch)*12 + tid] = s;
  }
  float u[36];
  #pragma unroll
  for (int i=0;i<36;i++) u[i] = 0.f;
  for (int n=0; n<nn; n++){
    float p[12];
    #pragma unroll
    for (int k=0;k<12;k++) p[k] = lp[n*16+k];
    #pragma unroll
    for (int c=0;c<3;c++){
      const int d = tid + (c<<8);
      const ushort fv = *(const ushort*)(sm + ((n*1536 + d*2) ^ ((n&7)<<4)));
      const float f = bf2f(fv);
      #pragma unroll
      for (int k=0;k<12;k++) u[k*3+c] += p[k]*f;
    }
  }
  float* up = a.Upart + (long)(b*43 + ch)*9216;
  #pragma unroll
  for (int k=0;k<12;k++)
    #pragma unroll
    for (int c=0;c<3;c++)
      up[k*768 + tid + (c<<8)] = u[k*3+c];
}

// ---------------- slot self-attention (one (b,h) pair) ------------------------
static __device__ void dev_slotattn(const MA& a, int b, int h, char* sm){
  float* qs = (float*)sm;      // [12][100]
  float* ks = qs + 1200;
  float* vs = ks + 1200;
  float* sc = vs + 1200;       // [12][16]
  const int tid = threadIdx.x;
  for (int idx = tid; idx < 1152; idx += 256){
    const int i = idx/96, d = idx - i*96;
    const float* base = a.qkvb + (long)(b*12+i)*2304 + h*96 + d;
    qs[i*100+d] = base[0];
    ks[i*100+d] = base[768];
    vs[i*100+d] = base[1536];
  }
  __syncthreads();
  if (tid < 144){
    const int i = tid/12, j = tid - i*12;
    float s = 0.f;
    #pragma unroll 8
    for (int d=0; d<96; d++) s += qs[i*100+d]*ks[j*100+d];
    sc[i*16+j] = s * 0.10206207261596575f;
  }
  __syncthreads();
  if (tid < 12){
    float mx = -1e30f;
    #pragma unroll
    for (int j=0;j<12;j++) mx = fmaxf(mx, sc[tid*16+j]);
    float e[12], ss = 0.f;
    #pragma unroll
    for (int j=0;j<12;j++){ e[j] = expf(sc[tid*16+j]-mx); ss += e[j]; }
    const float inv = 1.f/ss;
    #pragma unroll
    for (int j=0;j<12;j++) sc[tid*16+j] = e[j]*inv;
  }
  __syncthreads();
  for (int idx = tid; idx < 1152; idx += 256){
    const int i = idx/96, d = idx - i*96;
    float s = 0.f;
    #pragma unroll
    for (int j=0;j<12;j++) s += sc[i*16+j]*vs[j*100+d];
    a.ob[(long)(b*12+i)*768 + h*96 + d] = s;
  }
}

// ================== kernels ===================================================

// weight cvt (26496 jobs) + fn LN (43808 rows), merged
__global__ __launch_bounds__(256)
void cvtln_kernel(MA a){
  __shared__ float ts[1066];
  const int j = blockIdx.x, tid = threadIdx.x;
  if (j < 26496){ dev_cvt(a, j, ts); return; }
  const long r = j - 26496;
  const float* xr = a.features + r*768;
  float v0=xr[tid], v1=xr[tid+256], v2=xr[tid+512];
  float m, rs; ln_stats3(v0,v1,v2,ts,m,rs);
  a.fnb[r*768 + tid]     = f2bf((v0-m)*rs*a.nf_g[tid]     + a.nf_b[tid]);
  a.fnb[r*768 + tid+256] = f2bf((v1-m)*rs*a.nf_g[tid+256] + a.nf_b[tid+256]);
  a.fnb[r*768 + tid+512] = f2bf((v2-m)*rs*a.nf_g[tid+512] + a.nf_b[tid+512]);
}

// sn = ln(src, ns); h1 = ln(sn, ln1_t)   (grid 384)
__global__ __launch_bounds__(256)
void dualln_kernel(MA a, const float* src, int t){
  __shared__ float red[10];
  const long j = blockIdx.x;
  const int tid = threadIdx.x;
  const float* xr = src + j*768;
  float v0=xr[tid], v1=xr[tid+256], v2=xr[tid+512];
  float m, r; ln_stats3(v0,v1,v2,red,m,r);
  const float s0 = (v0-m)*r*a.ns_g[tid]     + a.ns_b[tid];
  const float s1 = (v1-m)*r*a.ns_g[tid+256] + a.ns_b[tid+256];
  const float s2 = (v2-m)*r*a.ns_g[tid+512] + a.ns_b[tid+512];
  a.sn[j*768+tid]=s0; a.sn[j*768+tid+256]=s1; a.sn[j*768+tid+512]=s2;
  float m2, r2; ln_stats3(s0,s1,s2,red,m2,r2);
  const float* g1 = a.b_ln1g + t*768; const float* bb1 = a.b_ln1b + t*768;
  a.h1[j*768+tid]     = (s0-m2)*r2*g1[tid]     + bb1[tid];
  a.h1[j*768+tid+256] = (s1-m2)*r2*g1[tid+256] + bb1[tid+256];
  a.h1[j*768+tid+512] = (s2-m2)*r2*g1[tid+512] + bb1[tid+512];
}

// generic LN (grid 384)
__global__ __launch_bounds__(256)
void ln_kernel(const float* __restrict__ x, const float* __restrict__ g,
               const float* __restrict__ b, float* __restrict__ y){
  __shared__ float red[10];
  const long j = blockIdx.x;
  const int tid = threadIdx.x;
  const float* xr = x + j*768;
  float v0=xr[tid], v1=xr[tid+256], v2=xr[tid+512];
  float m, r; ln_stats3(v0,v1,v2,red,m,r);
  y[j*768+tid]     = (v0-m)*r*g[tid]     + b[tid];
  y[j*768+tid+256] = (v1-m)*r*g[tid+256] + b[tid+256];
  y[j*768+tid+512] = (v2-m)*r*g[tid+512] + b[tid+512];
}

// generic tiled GEMM (grid = (M/64)*(N/64))
template<int FLAGS>
__global__ __launch_bounds__(256)
void gemm_kernel(const float* __restrict__ A, const ushort* __restrict__ BT,
                 float* C, ushort* Cbf, float* C2, int N, int K, int ntn,
                 const float* bias, const float* resid, float alpha){
  __shared__ char sm[18432];
  const int bm = blockIdx.x / ntn, bn = blockIdx.x - bm*ntn;
  dev_gemm_tile<FLAGS>(A, BT, C, Cbf, C2, N, K, bm<<6, bn<<6, bias, resid, alpha, sm);
}

// q2 (72 tiles) || qkv (216 tiles), grid 288
__global__ __launch_bounds__(256)
void qkvq2_kernel(MA a, int t){
  __shared__ char sm[18432];
  const int j = blockIdx.x;
  if (j < 72)
    dev_gemm_tile<F_OUTBF16|F_PAD16>(a.sn, a.WqkT, nullptr, a.q2bf, nullptr,
                                     768, 768, (j/12)<<6, (j%12)<<6, nullptr, nullptr, 1.f, sm);
  else {
    const int jj = j - 72;
    dev_gemm_tile<F_BIAS>(a.h1, a.WqkvT + (long)t*2304*768, a.qkvb, nullptr, nullptr,
                          2304, 768, (jj/36)<<6, (jj%36)<<6, a.b_bqkv + t*2304, nullptr, 1.f, sm);
  }
}

// sweep (1376) || slotattn (256); FINAL: grid 1376 masks only
template<bool FINAL>
__global__ __launch_bounds__(256)
void sweep_kernel(MA a){
  __shared__ char sm[51200];
  const int j = blockIdx.x;
  if (!FINAL && j >= 1376){ const int jj = j - 1376; dev_slotattn(a, jj>>3, jj&7, sm); return; }
  dev_sweep<FINAL>(a, j/43, j%43, sm);
}

// Ub = sum_ch Upart; invmass = 1/max(sum_ch massp, eps). grid 1153
__global__ __launch_bounds__(256)
void ureduce_kernel(MA a){
  const int tid = threadIdx.x;
  if (blockIdx.x < 1152){
    const long o = (long)blockIdx.x*256 + tid;   // < 294912
    const int b = (int)(o / 9216);
    const int r = (int)(o - (long)b*9216);
    const float* up = a.Upart + (long)b*43*9216 + r;
    float s = 0.f;
    #pragma unroll
    for (int c=0; c<43; c++) s += up[(long)c*9216];
    a.Ub[o] = s;
    return;
  }
  for (int r = tid; r < 384; r += 256){
    const int b = r/12, k = r - b*12;
    const float* mp = a.massp + (long)b*43*12 + k;
    float s = 0.f;
    #pragma unroll
    for (int c=0; c<43; c++) s += mp[c*12];
    a.invmass[r] = 1.f/fmaxf(s, 1e-8f);
  }
}

// s_in = m1@W2T + b2 + x1 + (Ub@WvT)*invmass   (grid 72)
__global__ __launch_bounds__(256)
void dual_kernel(MA a, int t){
  __shared__ char sm[18432];
  const int m0 = (blockIdx.x/12)<<6, n0 = (blockIdx.x%12)<<6;
  f32x4 acc1[2][2], acc2[2][2];
  #pragma unroll
  for (int i=0;i<2;i++){ acc1[i][0]=(f32x4){0,0,0,0}; acc1[i][1]=(f32x4){0,0,0,0};
                         acc2[i][0]=(f32x4){0,0,0,0}; acc2[i][1]=(f32x4){0,0,0,0}; }
  gemm_core(a.m1, a.W2T + (long)t*768*3072, 3072, m0, n0, acc1, sm);
  __syncthreads();
  gemm_core(a.Ub, a.WvT, 768, m0, n0, acc2, sm);
  const int tid=threadIdx.x, lane=tid&63, wid=tid>>6, wr=wid>>1, wc=wid&1;
  const float* b2 = a.b_b2 + t*768;
  #pragma unroll
  for (int fm=0; fm<2; fm++)
    #pragma unroll
    for (int fn=0; fn<2; fn++){
      const int col = n0 + (wc<<5) + (fn<<4) + (lane&15);
      const float bia = b2[col];
      #pragma unroll
      for (int j=0;j<4;j++){
        const int row = m0 + (wr<<5) + (fm<<4) + ((lane>>4)<<2) + j;
        a.s_in[(long)row*768 + col] =
            acc1[fm][fn][j] + bia + a.x1[(long)row*768 + col] + acc2[fm][fn][j]*a.invmass[row];
      }
    }
}

// ---------------- host -------------------------------------------------------
extern "C" void kernel_launch(void* const* d_in, const int* in_sizes, int n_in,
                              void* d_out, int out_size, void* d_ws, size_t ws_size,
                              hipStream_t stream){
  (void)in_sizes; (void)n_in; (void)out_size; (void)ws_size;
  MA a;
  a.features  = (const float*)d_in[0];
  a.slots_init= (const float*)d_in[1];
  a.nf_g = (const float*)d_in[2];  a.nf_b = (const float*)d_in[3];
  a.ns_g = (const float*)d_in[4];  a.ns_b = (const float*)d_in[5];
  a.Wq   = (const float*)d_in[6];  a.Wk   = (const float*)d_in[7];
  a.Wv   = (const float*)d_in[8];
  a.mg   = (const float*)d_in[9];  a.mb   = (const float*)d_in[10];
  a.mW1  = (const float*)d_in[11]; a.mb1  = (const float*)d_in[12];
  a.mW2  = (const float*)d_in[13]; a.mb2  = (const float*)d_in[14];
  a.b_ln1g = (const float*)d_in[15]; a.b_ln1b = (const float*)d_in[16];
  a.b_Wqkv = (const float*)d_in[17]; a.b_bqkv = (const float*)d_in[18];
  a.b_Wo   = (const float*)d_in[19]; a.b_bo   = (const float*)d_in[20];
  a.b_ln2g = (const float*)d_in[21]; a.b_ln2b = (const float*)d_in[22];
  a.b_W1   = (const float*)d_in[23]; a.b_b1   = (const float*)d_in[24];
  a.b_W2   = (const float*)d_in[25]; a.b_b2   = (const float*)d_in[26];

  char* ws = (char*)d_ws;
  size_t off = 0;
  auto alloc = [&](size_t bytes)->char*{
    char* p = ws + off; off += (bytes + 255) & ~(size_t)255; return p;
  };
  a.fnb   = (ushort*)alloc(43808ull*768*2);
  a.Wq_bf = (ushort*)alloc(589824ull*2);
  a.WqkT  = (ushort*)alloc(589824ull*2);
  a.WvT   = (ushort*)alloc(589824ull*2);
  a.WqkvT = (ushort*)alloc(3ull*2304*768*2);
  a.WoT   = (ushort*)alloc(3ull*589824*2);
  a.W1T   = (ushort*)alloc(3ull*3072*768*2);
  a.W2T   = (ushort*)alloc(3ull*3072*768*2);
  a.mW1T  = (ushort*)alloc(3072ull*768*2);
  a.mW2T  = (ushort*)alloc(3072ull*768*2);
  a.q2bf  = (ushort*)alloc(32ull*16*768*2);
  a.slots = (float*)alloc(294912ull*4);
  a.sn    = (float*)alloc(294912ull*4);
  a.h1    = (float*)alloc(294912ull*4);
  a.qkvb  = (float*)alloc(384ull*2304*4);
  a.ob    = (float*)alloc(294912ull*4);
  a.x1    = (float*)alloc(294912ull*4);
  a.h2    = (float*)alloc(294912ull*4);
  a.m1    = (float*)alloc(384ull*3072*4);
  a.s_in  = (float*)alloc(294912ull*4);
  a.h3    = (float*)alloc(294912ull*4);
  a.m2    = (float*)alloc(384ull*3072*4);
  a.Ub    = (float*)alloc(294912ull*4);
  a.Upart = (float*)alloc(32ull*43*9216*4);
  a.massp = (float*)alloc(32ull*43*12*4);
  a.invmass = (float*)alloc(384ull*4);
  a.out_slots = (float*)d_out;
  a.out_masks = (float*)d_out + 294912;

  const float SCALEF = 0.03608439182435161f; // 768^-0.5

  hipMemsetAsync(a.q2bf, 0, 32ull*16*768*2, stream);
  cvtln_kernel<<<dim3(26496 + 43808), dim3(256), 0, stream>>>(a);
  gemm_kernel<F_OUTBF16><<<dim3(144), dim3(256), 0, stream>>>(
      a.Wk, a.Wq_bf, nullptr, a.WqkT, nullptr, 768, 768, 12, nullptr, nullptr, SCALEF);

  for (int t = 0; t < 3; t++){
    const float* slots_src = (t == 0) ? a.slots_init : a.slots;
    dualln_kernel<<<dim3(384), dim3(256), 0, stream>>>(a, slots_src, t);
    qkvq2_kernel<<<dim3(288), dim3(256), 0, stream>>>(a, t);
    sweep_kernel<false><<<dim3(1632), dim3(256), 0, stream>>>(a);
    ureduce_kernel<<<dim3(1153), dim3(256), 0, stream>>>(a);
    gemm_kernel<F_BIAS|F_RESID><<<dim3(72), dim3(256), 0, stream>>>(
        a.ob, a.WoT + (size_t)t*589824, a.x1, nullptr, nullptr, 768, 768, 12,
        a.b_bo + t*768, a.sn, 1.f);
    ln_kernel<<<dim3(384), dim3(256), 0, stream>>>(a.x1, a.b_ln2g + t*768, a.b_ln2b + t*768, a.h2);
    gemm_kernel<F_BIAS|F_GELU><<<dim3(288), dim3(256), 0, stream>>>(
        a.h2, a.W1T + (size_t)t*3072*768, a.m1, nullptr, nullptr, 3072, 768, 48,
        a.b_b1 + t*3072, nullptr, 1.f);
    dual_kernel<<<dim3(72), dim3(256), 0, stream>>>(a, t);
    ln_kernel<<<dim3(384), dim3(256), 0, stream>>>(a.s_in, a.mg, a.mb, a.h3);
    gemm_kernel<F_BIAS|F_GELU><<<dim3(288), dim3(256), 0, stream>>>(
        a.h3, a.mW1T, a.m2, nullptr, nullptr, 3072, 768, 48, a.mb1, nullptr, 1.f);
    gemm_kernel<F_BIAS|F_RESID><<<dim3(72), dim3(256), 0, stream>>>(
        a.m2, a.mW2T, a.slots, nullptr, (t==2) ? a.out_slots : nullptr, 768, 3072, 12,
        a.mb2, slots_src, 1.f);
  }

  ln_kernel<<<dim3(384), dim3(256), 0, stream>>>(a.slots, a.ns_g, a.ns_b, a.sn);
  gemm_kernel<F_OUTBF16|F_PAD16><<<dim3(72), dim3(256), 0, stream>>>(
      a.sn, a.WqkT, nullptr, a.q2bf, nullptr, 768, 768, 12, nullptr, nullptr, 1.f);
  sweep_kernel<true><<<dim3(1376), dim3(256), 0, stream>>>(a);
}